// Round 7
// baseline (585.902 us; speedup 1.0000x reference)
//
#include <hip/hip_runtime.h>
#include <hip/hip_fp16.h>

#define NN 20000
#define NE 320000
#define NG 256
#define EB 1250   // NE / 256 exactly
#define SCB 80    // scan blocks per edge set (80*256 = 20480 >= NN)

// ---------------- CSR build ----------------

__global__ __launch_bounds__(256) void hist_both_kernel(
    const int* __restrict__ dis_dst, const int* __restrict__ edge_dst,
    int* __restrict__ cnt_d, int* __restrict__ cnt_e) {
  int b = blockIdx.x;
  if (b < EB) {
    int e = b * 256 + threadIdx.x;
    atomicAdd(&cnt_d[dis_dst[e]], 1);
  } else {
    int e = (b - EB) * 256 + threadIdx.x;
    atomicAdd(&cnt_e[edge_dst[e]], 1);
  }
}

// phase 1: per-256-chunk exclusive scan + chunk totals. grid = 2*SCB.
__global__ __launch_bounds__(256) void scan_local_kernel(
    const int* __restrict__ cnt_d, const int* __restrict__ cnt_e,
    int* __restrict__ rp_d, int* __restrict__ rp_e, int* __restrict__ totals) {
  int b = blockIdx.x;
  const int* counts = (b < SCB) ? cnt_d : cnt_e;
  int* rp = (b < SCB) ? rp_d : rp_e;
  int base = ((b < SCB) ? b : b - SCB) * 256;
  int t = threadIdx.x;
  int lane = t & 63;
  int w = t >> 6;
  int idx = base + t;
  int v = (idx < NN) ? counts[idx] : 0;
  int incl = v;
#pragma unroll
  for (int off = 1; off < 64; off <<= 1) {
    int g = __shfl_up(incl, off);
    if (lane >= off) incl += g;
  }
  __shared__ int wsum[4];
  if (lane == 63) wsum[w] = incl;
  __syncthreads();
  int woff = 0;
  for (int j = 0; j < 4; ++j)
    if (j < w) woff += wsum[j];
  if (idx < NN) rp[idx] = woff + incl - v;  // exclusive within chunk
  if (t == 255) totals[b] = woff + incl;
}

// phase 2: add prefix of chunk totals. grid = 2*SCB.
__global__ __launch_bounds__(256) void scan_apply_kernel(
    const int* __restrict__ totals, int* __restrict__ rp_d,
    int* __restrict__ rp_e) {
  int b = blockIdx.x;
  int set = (b < SCB) ? 0 : 1;
  int lb = (b < SCB) ? b : b - SCB;
  const int* tt = totals + set * SCB;
  int t = threadIdx.x;
  __shared__ int soff, stot;
  if (t < 64) {
    int lane = t;
    int v = (lane < lb) ? tt[lane] : 0;               // lane < 64 < SCB? SCB=80
    int a = (lane < SCB) ? tt[lane] : 0;
    int l2 = 64 + lane;
    if (l2 < SCB) {
      if (l2 < lb) v += tt[l2];
      a += tt[l2];
    }
#pragma unroll
    for (int off = 1; off < 64; off <<= 1) {
      v += __shfl_xor(v, off);
      a += __shfl_xor(a, off);
    }
    if (lane == 0) { soff = v; stot = a; }
  }
  __syncthreads();
  int* rp = (set == 0) ? rp_d : rp_e;
  int idx = lb * 256 + t;
  if (idx < NN) rp[idx] += soff;
  if (t == 0 && lb == SCB - 1) rp[NN] = stot;
}

__global__ __launch_bounds__(256) void scatter_both_kernel(
    const int* __restrict__ dis_idx, const int* __restrict__ edge_idx,
    const int* __restrict__ rp_d, const int* __restrict__ rp_e,
    int* __restrict__ cur_d, int* __restrict__ cur_e,
    int* __restrict__ s_d, int* __restrict__ s_e) {
  int b = blockIdx.x;
  if (b < EB) {
    int e = b * 256 + threadIdx.x;
    int d = dis_idx[NE + e];
    int pos = rp_d[d] + atomicAdd(&cur_d[d], 1);
    s_d[pos] = dis_idx[e];
  } else {
    int e = (b - EB) * 256 + threadIdx.x;
    int d = edge_idx[NE + e];
    int pos = rp_e[d] + atomicAdd(&cur_e[d], 1);
    s_e[pos] = edge_idx[e];
  }
}

// ---------------- first GEMM + attention sums (persistent) ----------------

__global__ __launch_bounds__(256) void gemm_attn_kernel(
    const float* __restrict__ x, const float* __restrict__ W,
    const float* __restrict__ att_src, const float* __restrict__ att_dst,
    __half* __restrict__ h, float* __restrict__ a_src, float* __restrict__ a_dst) {
  __shared__ float ws[64 * 64];
  int t = threadIdx.x;
  int lr = t >> 6;
  int c = t & 63;
  const float4* W4 = (const float4*)W;
  float4* ws4 = (float4*)ws;
  for (int k = t; k < 1024; k += 256) ws4[k] = W4[k];
  float asv = att_src[c], adv = att_dst[c];
  __syncthreads();
  for (int n = blockIdx.x * 4 + lr; n < NN; n += gridDim.x * 4) {
    float xv = x[n * 64 + c];
    float acc = 0.f;
#pragma unroll
    for (int k = 0; k < 64; ++k) {
      float xk = __shfl(xv, k);
      acc = fmaf(xk, ws[k * 64 + c], acc);
    }
    h[n * 64 + c] = __float2half(acc);
    float ts = acc * asv;
    float td = acc * adv;
#pragma unroll
    for (int off = 1; off < 8; off <<= 1) {
      ts += __shfl_xor(ts, off);
      td += __shfl_xor(td, off);
    }
    if ((c & 7) == 0) {
      a_src[n * 8 + (c >> 3)] = ts;
      a_dst[n * 8 + (c >> 3)] = td;
    }
  }
}

// ---------------- fused agg (+ optional next-conv GEMM/attn), persistent ----
// One wave per dst node. lane = (half, p): channels {2p, 2p+1}; half 0 even
// edges, half 1 odd edges. h gathered as __half2. Accumulation fp32.
template <int H, bool RELU, int HN>
__global__ __launch_bounds__(256) void agg_fused_kernel(
    const __half* __restrict__ h, const float* __restrict__ a_src,
    const float* __restrict__ a_dst, const int* __restrict__ rowptr,
    const int* __restrict__ srcs, const float* __restrict__ bias,
    __half* __restrict__ out_h, float* __restrict__ out_f,
    const float* __restrict__ Wn, const float* __restrict__ asn,
    const float* __restrict__ adn, float* __restrict__ a_src_n,
    float* __restrict__ a_dst_n) {
  extern __shared__ float ws[];
  int t = threadIdx.x;
  int lane = t & 63;
  int half = lane >> 5;
  int p = lane & 31;  // channel pair; channels 2p, 2p+1 (same head always)
  if (HN != 0) {
    const float4* W4 = (const float4*)Wn;
    float4* ws4 = (float4*)ws;
    for (int k = t; k < 1024; k += 256) ws4[k] = W4[k];
  }
  const int hd = (H == 8) ? (p >> 2) : 0;
  float bx = bias[2 * p], by = bias[2 * p + 1];
  float anx = 0.f, any = 0.f, adx = 0.f, ady = 0.f;
  if (HN != 0) {
    anx = asn[2 * p]; any = asn[2 * p + 1];
    adx = adn[2 * p]; ady = adn[2 * p + 1];
    __syncthreads();
  }
  const float2* ws2 = (const float2*)ws;

  for (int i = blockIdx.x * 4 + (t >> 6); i < NN; i += gridDim.x * 4) {
    float ad = a_dst[i * H + hd];
    int j0 = rowptr[i], jend = rowptr[i + 1];
    int deg = jend - j0;

    float denom = 0.f, accx = 0.f, accy = 0.f;
    for (int b0 = 0; b0 < deg; b0 += 64) {
      int li = j0 + b0 + lane;
      if (li > jend - 1) li = jend - 1;
      int sIdx = srcs[li];
      int blkn = deg - b0;
      if (blkn > 64) blkn = 64;
      for (int r0 = 0; r0 < blkn; r0 += 16) {
        int sv[8];
        float asv[8];
        __half2 hv[8];
#pragma unroll
        for (int u = 0; u < 8; ++u) sv[u] = __shfl(sIdx, r0 + 2 * u + half);
#pragma unroll
        for (int u = 0; u < 8; ++u) asv[u] = a_src[sv[u] * H + hd];
#pragma unroll
        for (int u = 0; u < 8; ++u)
          hv[u] = *(const __half2*)&h[sv[u] * 64 + 2 * p];
#pragma unroll
        for (int u = 0; u < 8; ++u) {
          int r = r0 + 2 * u + half;
          float ll = asv[u] + ad;
          ll = (ll > 0.f) ? ll : 0.2f * ll;
          float ww = __expf(ll);
          ww = (r < blkn) ? ww : 0.f;
          float2 hf = __half22float2(hv[u]);
          denom += ww;
          accx = fmaf(ww, hf.x, accx);
          accy = fmaf(ww, hf.y, accy);
        }
      }
    }
    // combine halves
    denom += __shfl_xor(denom, 32);
    accx += __shfl_xor(accx, 32);
    accy += __shfl_xor(accy, 32);
    // self loop
    {
      float l = a_src[i * H + hd] + ad;
      l = (l > 0.f) ? l : 0.2f * l;
      float w = __expf(l);
      float2 hs = __half22float2(*(const __half2*)&h[i * 64 + 2 * p]);
      denom += w;
      accx = fmaf(w, hs.x, accx);
      accy = fmaf(w, hs.y, accy);
    }
    float inv = 1.f / denom;
    float ox = accx * inv + bx;
    float oy = accy * inv + by;
    if (RELU) {
      ox = fmaxf(ox, 0.f);
      oy = fmaxf(oy, 0.f);
    }
    if (HN == 0) {
      if (half == 0) *(float2*)&out_f[i * 64 + 2 * p] = make_float2(ox, oy);
      continue;
    }
    // fused next GEMM: o @ Wn
    float a2x = 0.f, a2y = 0.f;
#pragma unroll
    for (int k = 0; k < 64; ++k) {
      float ok = __shfl((k & 1) ? oy : ox, k >> 1);
      float2 wv = ws2[k * 32 + p];
      a2x = fmaf(ok, wv.x, a2x);
      a2y = fmaf(ok, wv.y, a2y);
    }
    if (half == 0)
      *(__half2*)&out_h[i * 64 + 2 * p] = __floats2half2_rn(a2x, a2y);
    float ts = a2x * anx + a2y * any;
    float td = a2x * adx + a2y * ady;
    const int gsp = (HN == 8) ? 4 : 32;
#pragma unroll
    for (int off = 1; off < gsp; off <<= 1) {
      ts += __shfl_xor(ts, off);
      td += __shfl_xor(td, off);
    }
    if (half == 0 && (p & (gsp - 1)) == 0) {
      int hdn = p / gsp;
      a_src_n[i * HN + hdn] = ts;
      a_dst_n[i * HN + hdn] = td;
    }
  }
}

// ---------------- fused pool + readout: one block per graph ----------------

__global__ __launch_bounds__(256) void poolread_kernel(
    const float* __restrict__ xF, const int* __restrict__ batch,
    const float* __restrict__ Wm1, const float* __restrict__ bm1,
    const float* __restrict__ Wm2, const float* __restrict__ bm2,
    float* __restrict__ out) {
  __shared__ float sred[4][64];
  __shared__ int se[2];
  int g = blockIdx.x;
  int t = threadIdx.x;
  int w = t >> 6, c = t & 63;
  if (t < 2) {
    int target = g + t;  // lower_bound(batch, target)
    int lo = 0, hi = NN;
    while (lo < hi) {
      int m = (lo + hi) >> 1;
      if (batch[m] < target) lo = m + 1;
      else hi = m;
    }
    se[t] = lo;
  }
  __syncthreads();
  int s = se[0], e = se[1];
  float acc = 0.f;
  for (int n = s + w; n < e; n += 4) acc += xF[n * 64 + c];
  sred[w][c] = acc;
  __syncthreads();
  if (w == 0) {
    float v = sred[0][c] + sred[1][c] + sred[2][c] + sred[3][c];
    float cv = fmaxf((float)(e - s), 1.f);
    float gv = v / cv;
    float a1 = 0.f;
#pragma unroll
    for (int k = 0; k < 64; ++k) {
      float bk = __shfl(gv, k);
      if (c < 32) a1 = fmaf(bk, Wm1[k * 32 + c], a1);
    }
    float m = 0.f;
    if (c < 32) {
      float hid = fmaxf(a1 + bm1[c], 0.f);
      m = hid * Wm2[c];
    }
#pragma unroll
    for (int off = 32; off >= 1; off >>= 1) m += __shfl_xor(m, off);
    if (c == 0) out[g] = m + bm2[0];
  }
}

// ---------------- launch ----------------

extern "C" void kernel_launch(void* const* d_in, const int* in_sizes, int n_in,
                              void* d_out, int out_size, void* d_ws, size_t ws_size,
                              hipStream_t stream) {
  const float* x0       = (const float*)d_in[0];
  const int*   edge_idx = (const int*)d_in[1];
  const int*   batch    = (const int*)d_in[3];
  const int*   dis_idx  = (const int*)d_in[6];
  const float* W1  = (const float*)d_in[7];
  const float* as1 = (const float*)d_in[8];
  const float* ad1 = (const float*)d_in[9];
  const float* b1  = (const float*)d_in[10];
  const float* W2  = (const float*)d_in[11];
  const float* as2 = (const float*)d_in[12];
  const float* ad2 = (const float*)d_in[13];
  const float* b2  = (const float*)d_in[14];
  const float* Wm1 = (const float*)d_in[19];
  const float* bm1 = (const float*)d_in[20];
  const float* Wm2 = (const float*)d_in[21];
  const float* bm2 = (const float*)d_in[22];
  float* out = (float*)d_out;

  char* ws = (char*)d_ws;
  size_t off = 0;
  auto alloc = [&](size_t bytes) {
    void* p = ws + off;
    off += (bytes + 255) & ~(size_t)255;
    return p;
  };
  __half* hA   = (__half*)alloc(NN * 64 * 2);
  __half* hB   = (__half*)alloc(NN * 64 * 2);
  float* xF    = (float*)alloc(NN * 64 * 4);
  float* asA   = (float*)alloc(NN * 8 * 4);
  float* adA   = (float*)alloc(NN * 8 * 4);
  float* asB   = (float*)alloc(NN * 8 * 4);
  float* adB   = (float*)alloc(NN * 8 * 4);
  int* rp_d    = (int*)alloc((NN + 1) * 4);
  int* s_d     = (int*)alloc(NE * 4);
  int* rp_e    = (int*)alloc((NN + 1) * 4);
  int* s_e     = (int*)alloc(NE * 4);
  int* totals  = (int*)alloc(2 * SCB * 4);
  // contiguous zero region: cnt_d, cur_d, cnt_e, cur_e
  char* zero0  = ws + off;
  int* cnt_d   = (int*)alloc(NN * 4);
  int* cur_d   = (int*)alloc(NN * 4);
  int* cnt_e   = (int*)alloc(NN * 4);
  int* cur_e   = (int*)alloc(NN * 4);
  size_t zbytes = (size_t)((char*)(ws + off) - zero0);

  const size_t SH = 64 * 64 * sizeof(float);
  const int PG = 2048;  // persistent grid: 8 blocks/CU x 256 CUs

  hipMemsetAsync(zero0, 0, zbytes, stream);
  hist_both_kernel<<<2 * EB, 256, 0, stream>>>(dis_idx + NE, edge_idx + NE,
                                               cnt_d, cnt_e);
  scan_local_kernel<<<2 * SCB, 256, 0, stream>>>(cnt_d, cnt_e, rp_d, rp_e, totals);
  scan_apply_kernel<<<2 * SCB, 256, 0, stream>>>(totals, rp_d, rp_e);
  scatter_both_kernel<<<2 * EB, 256, 0, stream>>>(dis_idx, edge_idx, rp_d, rp_e,
                                                  cur_d, cur_e, s_d, s_e);

  // first conv1 GEMM + attention sums (H=8)
  gemm_attn_kernel<<<PG, 256, 0, stream>>>(x0, W1, as1, ad1, hA, asA, adA);

  // 12 convs; even = conv1 (H=8, relu, fuse W2), odd = conv2 (H=1, fuse W1)
  for (int k = 0; k < 12; ++k) {
    const int* rp = (((k >> 1) & 1) == 0) ? rp_d : rp_e;
    const int* ss = (((k >> 1) & 1) == 0) ? s_d : s_e;
    if ((k & 1) == 0) {
      agg_fused_kernel<8, true, 1><<<PG, 256, SH, stream>>>(
          hA, asA, adA, rp, ss, b1, hB, nullptr, W2, as2, ad2, asB, adB);
    } else if (k < 11) {
      agg_fused_kernel<1, false, 8><<<PG, 256, SH, stream>>>(
          hB, asB, adB, rp, ss, b2, hA, nullptr, W1, as1, ad1, asA, adA);
    } else {
      agg_fused_kernel<1, false, 0><<<PG, 256, 0, stream>>>(
          hB, asB, adB, rp, ss, b2, nullptr, xF, nullptr, nullptr, nullptr,
          nullptr, nullptr);
    }
  }

  // fused global mean pool + readout MLP
  poolread_kernel<<<NG, 256, 0, stream>>>(xF, batch, Wm1, bm1, Wm2, bm2, out);
}

// Round 8
// 401.356 us; speedup vs baseline: 1.4598x; 1.4598x over previous
//
#include <hip/hip_runtime.h>
#include <hip/hip_fp16.h>

#define NN 20000
#define NE 320000
#define NG 256
#define EB 1250   // NE / 256 exactly
#define SCB 80    // scan blocks per edge set (80*256 = 20480 >= NN)

// ---------------- CSR build ----------------

__global__ __launch_bounds__(256) void hist_both_kernel(
    const int* __restrict__ dis_dst, const int* __restrict__ edge_dst,
    int* __restrict__ cnt_d, int* __restrict__ cnt_e) {
  int b = blockIdx.x;
  if (b < EB) {
    int e = b * 256 + threadIdx.x;
    atomicAdd(&cnt_d[dis_dst[e]], 1);
  } else {
    int e = (b - EB) * 256 + threadIdx.x;
    atomicAdd(&cnt_e[edge_dst[e]], 1);
  }
}

// phase 1: per-256-chunk exclusive scan + chunk totals. grid = 2*SCB.
__global__ __launch_bounds__(256) void scan_local_kernel(
    const int* __restrict__ cnt_d, const int* __restrict__ cnt_e,
    int* __restrict__ rp_d, int* __restrict__ rp_e, int* __restrict__ totals) {
  int b = blockIdx.x;
  const int* counts = (b < SCB) ? cnt_d : cnt_e;
  int* rp = (b < SCB) ? rp_d : rp_e;
  int base = ((b < SCB) ? b : b - SCB) * 256;
  int t = threadIdx.x;
  int lane = t & 63;
  int w = t >> 6;
  int idx = base + t;
  int v = (idx < NN) ? counts[idx] : 0;
  int incl = v;
#pragma unroll
  for (int off = 1; off < 64; off <<= 1) {
    int g = __shfl_up(incl, off);
    if (lane >= off) incl += g;
  }
  __shared__ int wsum[4];
  if (lane == 63) wsum[w] = incl;
  __syncthreads();
  int woff = 0;
  for (int j = 0; j < 4; ++j)
    if (j < w) woff += wsum[j];
  if (idx < NN) rp[idx] = woff + incl - v;  // exclusive within chunk
  if (t == 255) totals[b] = woff + incl;
}

// phase 2: add prefix of chunk totals. grid = 2*SCB.
__global__ __launch_bounds__(256) void scan_apply_kernel(
    const int* __restrict__ totals, int* __restrict__ rp_d,
    int* __restrict__ rp_e) {
  int b = blockIdx.x;
  int set = (b < SCB) ? 0 : 1;
  int lb = (b < SCB) ? b : b - SCB;
  const int* tt = totals + set * SCB;
  int t = threadIdx.x;
  __shared__ int soff, stot;
  if (t < 64) {
    int lane = t;
    int v = (lane < lb) ? tt[lane] : 0;
    int a = (lane < SCB) ? tt[lane] : 0;
    int l2 = 64 + lane;
    if (l2 < SCB) {
      if (l2 < lb) v += tt[l2];
      a += tt[l2];
    }
#pragma unroll
    for (int off = 1; off < 64; off <<= 1) {
      v += __shfl_xor(v, off);
      a += __shfl_xor(a, off);
    }
    if (lane == 0) { soff = v; stot = a; }
  }
  __syncthreads();
  int* rp = (set == 0) ? rp_d : rp_e;
  int idx = lb * 256 + t;
  if (idx < NN) rp[idx] += soff;
  if (t == 0 && lb == SCB - 1) rp[NN] = stot;
}

__global__ __launch_bounds__(256) void scatter_both_kernel(
    const int* __restrict__ dis_idx, const int* __restrict__ edge_idx,
    const int* __restrict__ rp_d, const int* __restrict__ rp_e,
    int* __restrict__ cur_d, int* __restrict__ cur_e,
    int* __restrict__ s_d, int* __restrict__ s_e) {
  int b = blockIdx.x;
  if (b < EB) {
    int e = b * 256 + threadIdx.x;
    int d = dis_idx[NE + e];
    int pos = rp_d[d] + atomicAdd(&cur_d[d], 1);
    s_d[pos] = dis_idx[e];
  } else {
    int e = (b - EB) * 256 + threadIdx.x;
    int d = edge_idx[NE + e];
    int pos = rp_e[d] + atomicAdd(&cur_e[d], 1);
    s_e[pos] = edge_idx[e];
  }
}

// ---------------- first GEMM + attention sums ----------------

__global__ __launch_bounds__(256) void gemm_attn_kernel(
    const float* __restrict__ x, const float* __restrict__ W,
    const float* __restrict__ att_src, const float* __restrict__ att_dst,
    __half* __restrict__ h, float* __restrict__ a_src, float* __restrict__ a_dst) {
  __shared__ float ws[64 * 64];
  int t = threadIdx.x;
  int lr = t >> 6;
  int c = t & 63;
  int n = blockIdx.x * 4 + lr;
  const float4* W4 = (const float4*)W;
  float4* ws4 = (float4*)ws;
  for (int k = t; k < 1024; k += 256) ws4[k] = W4[k];
  float xv = x[n * 64 + c];
  __syncthreads();
  float acc = 0.f;
#pragma unroll
  for (int k = 0; k < 64; ++k) {
    float xk = __shfl(xv, k);
    acc = fmaf(xk, ws[k * 64 + c], acc);
  }
  h[n * 64 + c] = __float2half(acc);
  float ts = acc * att_src[c];
  float td = acc * att_dst[c];
#pragma unroll
  for (int off = 1; off < 8; off <<= 1) {
    ts += __shfl_xor(ts, off);
    td += __shfl_xor(td, off);
  }
  if ((c & 7) == 0) {
    a_src[n * 8 + (c >> 3)] = ts;
    a_dst[n * 8 + (c >> 3)] = td;
  }
}

// ---------------- fused agg: TWO nodes per wave, interleaved ----------------
// lane = (half, p): channels {2p,2p+1}; half 0 even edges, half 1 odd edges.
// Wave owns nodes iA, iB=iA+1; all loads for both issued before consumption.
template <int H, bool RELU, int HN>
__global__ __launch_bounds__(256) void agg_fused_kernel(
    const __half* __restrict__ h, const float* __restrict__ a_src,
    const float* __restrict__ a_dst, const int* __restrict__ rowptr,
    const int* __restrict__ srcs, const float* __restrict__ bias,
    __half* __restrict__ out_h, float* __restrict__ out_f,
    const float* __restrict__ Wn, const float* __restrict__ asn,
    const float* __restrict__ adn, float* __restrict__ a_src_n,
    float* __restrict__ a_dst_n) {
  extern __shared__ float ws[];
  int t = threadIdx.x;
  int lane = t & 63;
  int half = lane >> 5;
  int p = lane & 31;
  if (HN != 0) {
    const float4* W4 = (const float4*)Wn;
    float4* ws4 = (float4*)ws;
    for (int k = t; k < 1024; k += 256) ws4[k] = W4[k];
    __syncthreads();
  }
  const int hd = (H == 8) ? (p >> 2) : 0;
  const int iA = blockIdx.x * 8 + (t >> 6) * 2;
  const int iB = iA + 1;

  // independent early loads
  int j0A = rowptr[iA], jeA = rowptr[iA + 1], jeB = rowptr[iB + 1];
  int j0B = jeA;
  float adA = a_dst[iA * H + hd], adB = a_dst[iB * H + hd];
  float asSA = a_src[iA * H + hd], asSB = a_src[iB * H + hd];
  __half2 hsA = *(const __half2*)&h[iA * 64 + 2 * p];
  __half2 hsB = *(const __half2*)&h[iB * 64 + 2 * p];

  int degA = jeA - j0A, degB = jeB - j0B;
  int sIdxA = 0, sIdxB = 0;
  if (degA > 0) {
    int li = j0A + lane;
    if (li > jeA - 1) li = jeA - 1;
    sIdxA = srcs[li];
  }
  if (degB > 0) {
    int li = j0B + lane;
    if (li > jeB - 1) li = jeB - 1;
    sIdxB = srcs[li];
  }
  int bA = degA < 64 ? degA : 64;
  int bB = degB < 64 ? degB : 64;
  int mx = bA > bB ? bA : bB;

  float denA = 0.f, axA = 0.f, ayA = 0.f;
  float denB = 0.f, axB = 0.f, ayB = 0.f;

  for (int r0 = 0; r0 < mx; r0 += 16) {
    int svA[8], svB[8];
    float asvA[8], asvB[8];
    __half2 hvA[8], hvB[8];
    bool doA = r0 < bA, doB = r0 < bB;
    if (doA) {
#pragma unroll
      for (int u = 0; u < 8; ++u) svA[u] = __shfl(sIdxA, r0 + 2 * u + half);
#pragma unroll
      for (int u = 0; u < 8; ++u) asvA[u] = a_src[svA[u] * H + hd];
#pragma unroll
      for (int u = 0; u < 8; ++u)
        hvA[u] = *(const __half2*)&h[svA[u] * 64 + 2 * p];
    }
    if (doB) {
#pragma unroll
      for (int u = 0; u < 8; ++u) svB[u] = __shfl(sIdxB, r0 + 2 * u + half);
#pragma unroll
      for (int u = 0; u < 8; ++u) asvB[u] = a_src[svB[u] * H + hd];
#pragma unroll
      for (int u = 0; u < 8; ++u)
        hvB[u] = *(const __half2*)&h[svB[u] * 64 + 2 * p];
    }
    if (doA) {
#pragma unroll
      for (int u = 0; u < 8; ++u) {
        int r = r0 + 2 * u + half;
        float ll = asvA[u] + adA;
        ll = (ll > 0.f) ? ll : 0.2f * ll;
        float ww = __expf(ll);
        ww = (r < bA) ? ww : 0.f;
        float2 hf = __half22float2(hvA[u]);
        denA += ww;
        axA = fmaf(ww, hf.x, axA);
        ayA = fmaf(ww, hf.y, ayA);
      }
    }
    if (doB) {
#pragma unroll
      for (int u = 0; u < 8; ++u) {
        int r = r0 + 2 * u + half;
        float ll = asvB[u] + adB;
        ll = (ll > 0.f) ? ll : 0.2f * ll;
        float ww = __expf(ll);
        ww = (r < bB) ? ww : 0.f;
        float2 hf = __half22float2(hvB[u]);
        denB += ww;
        axB = fmaf(ww, hf.x, axB);
        ayB = fmaf(ww, hf.y, ayB);
      }
    }
  }
  // rare tail (deg > 64)
  for (int b0 = 64; b0 < degA; b0 += 64) {
    int li = j0A + b0 + lane;
    if (li > jeA - 1) li = jeA - 1;
    int sIdx = srcs[li];
    int blkn = degA - b0;
    if (blkn > 64) blkn = 64;
    for (int r0 = 0; r0 < blkn; r0 += 16) {
#pragma unroll
      for (int u = 0; u < 8; ++u) {
        int r = r0 + 2 * u + half;
        int s = __shfl(sIdx, r);
        float ll = a_src[s * H + hd] + adA;
        ll = (ll > 0.f) ? ll : 0.2f * ll;
        float ww = __expf(ll);
        ww = (r < blkn) ? ww : 0.f;
        float2 hf = __half22float2(*(const __half2*)&h[s * 64 + 2 * p]);
        denA += ww;
        axA = fmaf(ww, hf.x, axA);
        ayA = fmaf(ww, hf.y, ayA);
      }
    }
  }
  for (int b0 = 64; b0 < degB; b0 += 64) {
    int li = j0B + b0 + lane;
    if (li > jeB - 1) li = jeB - 1;
    int sIdx = srcs[li];
    int blkn = degB - b0;
    if (blkn > 64) blkn = 64;
    for (int r0 = 0; r0 < blkn; r0 += 16) {
#pragma unroll
      for (int u = 0; u < 8; ++u) {
        int r = r0 + 2 * u + half;
        int s = __shfl(sIdx, r);
        float ll = a_src[s * H + hd] + adB;
        ll = (ll > 0.f) ? ll : 0.2f * ll;
        float ww = __expf(ll);
        ww = (r < blkn) ? ww : 0.f;
        float2 hf = __half22float2(*(const __half2*)&h[s * 64 + 2 * p]);
        denB += ww;
        axB = fmaf(ww, hf.x, axB);
        ayB = fmaf(ww, hf.y, ayB);
      }
    }
  }

  // combine halves
  denA += __shfl_xor(denA, 32);
  axA += __shfl_xor(axA, 32);
  ayA += __shfl_xor(ayA, 32);
  denB += __shfl_xor(denB, 32);
  axB += __shfl_xor(axB, 32);
  ayB += __shfl_xor(ayB, 32);
  // self loops
  {
    float l = asSA + adA;
    l = (l > 0.f) ? l : 0.2f * l;
    float w = __expf(l);
    float2 hf = __half22float2(hsA);
    denA += w;
    axA = fmaf(w, hf.x, axA);
    ayA = fmaf(w, hf.y, ayA);
    l = asSB + adB;
    l = (l > 0.f) ? l : 0.2f * l;
    w = __expf(l);
    hf = __half22float2(hsB);
    denB += w;
    axB = fmaf(w, hf.x, axB);
    ayB = fmaf(w, hf.y, ayB);
  }
  float bx = bias[2 * p], by = bias[2 * p + 1];
  float invA = 1.f / denA, invB = 1.f / denB;
  float oxA = axA * invA + bx, oyA = ayA * invA + by;
  float oxB = axB * invB + bx, oyB = ayB * invB + by;
  if (RELU) {
    oxA = fmaxf(oxA, 0.f); oyA = fmaxf(oyA, 0.f);
    oxB = fmaxf(oxB, 0.f); oyB = fmaxf(oyB, 0.f);
  }
  if (HN == 0) {
    if (half == 0) {
      *(float2*)&out_f[iA * 64 + 2 * p] = make_float2(oxA, oyA);
      *(float2*)&out_f[iB * 64 + 2 * p] = make_float2(oxB, oyB);
    }
    return;
  }
  // fused next GEMM, split across halves (32 iters) + interleaved A/B
  const float2* ws2 = (const float2*)ws;
  float a2xA = 0.f, a2yA = 0.f, a2xB = 0.f, a2yB = 0.f;
#pragma unroll
  for (int kk = 0; kk < 32; ++kk) {
    int k = half * 32 + kk;
    float okA = __shfl((k & 1) ? oyA : oxA, k >> 1);
    float okB = __shfl((k & 1) ? oyB : oxB, k >> 1);
    float2 wv = ws2[k * 32 + p];
    a2xA = fmaf(okA, wv.x, a2xA);
    a2yA = fmaf(okA, wv.y, a2yA);
    a2xB = fmaf(okB, wv.x, a2xB);
    a2yB = fmaf(okB, wv.y, a2yB);
  }
  a2xA += __shfl_xor(a2xA, 32);
  a2yA += __shfl_xor(a2yA, 32);
  a2xB += __shfl_xor(a2xB, 32);
  a2yB += __shfl_xor(a2yB, 32);
  if (half == 0) {
    *(__half2*)&out_h[iA * 64 + 2 * p] = __floats2half2_rn(a2xA, a2yA);
    *(__half2*)&out_h[iB * 64 + 2 * p] = __floats2half2_rn(a2xB, a2yB);
  }
  float anx = asn[2 * p], any = asn[2 * p + 1];
  float adx = adn[2 * p], ady = adn[2 * p + 1];
  float tsA = a2xA * anx + a2yA * any;
  float tdA = a2xA * adx + a2yA * ady;
  float tsB = a2xB * anx + a2yB * any;
  float tdB = a2xB * adx + a2yB * ady;
  const int gsp = (HN == 8) ? 4 : 32;
#pragma unroll
  for (int off = 1; off < gsp; off <<= 1) {
    tsA += __shfl_xor(tsA, off);
    tdA += __shfl_xor(tdA, off);
    tsB += __shfl_xor(tsB, off);
    tdB += __shfl_xor(tdB, off);
  }
  if (half == 0 && (p & (gsp - 1)) == 0) {
    int hdn = p / gsp;
    a_src_n[iA * HN + hdn] = tsA;
    a_dst_n[iA * HN + hdn] = tdA;
    a_src_n[iB * HN + hdn] = tsB;
    a_dst_n[iB * HN + hdn] = tdB;
  }
}

// ---------------- fused pool + readout: one block per graph ----------------

__global__ __launch_bounds__(256) void poolread_kernel(
    const float* __restrict__ xF, const int* __restrict__ batch,
    const float* __restrict__ Wm1, const float* __restrict__ bm1,
    const float* __restrict__ Wm2, const float* __restrict__ bm2,
    float* __restrict__ out) {
  __shared__ float sred[4][64];
  __shared__ int se[2];
  int g = blockIdx.x;
  int t = threadIdx.x;
  int w = t >> 6, c = t & 63;
  if (t < 2) {
    int target = g + t;
    int lo = 0, hi = NN;
    while (lo < hi) {
      int m = (lo + hi) >> 1;
      if (batch[m] < target) lo = m + 1;
      else hi = m;
    }
    se[t] = lo;
  }
  __syncthreads();
  int s = se[0], e = se[1];
  float acc = 0.f;
  for (int n = s + w; n < e; n += 4) acc += xF[n * 64 + c];
  sred[w][c] = acc;
  __syncthreads();
  if (w == 0) {
    float v = sred[0][c] + sred[1][c] + sred[2][c] + sred[3][c];
    float cv = fmaxf((float)(e - s), 1.f);
    float gv = v / cv;
    float a1 = 0.f;
#pragma unroll
    for (int k = 0; k < 64; ++k) {
      float bk = __shfl(gv, k);
      if (c < 32) a1 = fmaf(bk, Wm1[k * 32 + c], a1);
    }
    float m = 0.f;
    if (c < 32) {
      float hid = fmaxf(a1 + bm1[c], 0.f);
      m = hid * Wm2[c];
    }
#pragma unroll
    for (int off = 32; off >= 1; off >>= 1) m += __shfl_xor(m, off);
    if (c == 0) out[g] = m + bm2[0];
  }
}

// ---------------- launch ----------------

extern "C" void kernel_launch(void* const* d_in, const int* in_sizes, int n_in,
                              void* d_out, int out_size, void* d_ws, size_t ws_size,
                              hipStream_t stream) {
  const float* x0       = (const float*)d_in[0];
  const int*   edge_idx = (const int*)d_in[1];
  const int*   batch    = (const int*)d_in[3];
  const int*   dis_idx  = (const int*)d_in[6];
  const float* W1  = (const float*)d_in[7];
  const float* as1 = (const float*)d_in[8];
  const float* ad1 = (const float*)d_in[9];
  const float* b1  = (const float*)d_in[10];
  const float* W2  = (const float*)d_in[11];
  const float* as2 = (const float*)d_in[12];
  const float* ad2 = (const float*)d_in[13];
  const float* b2  = (const float*)d_in[14];
  const float* Wm1 = (const float*)d_in[19];
  const float* bm1 = (const float*)d_in[20];
  const float* Wm2 = (const float*)d_in[21];
  const float* bm2 = (const float*)d_in[22];
  float* out = (float*)d_out;

  char* ws = (char*)d_ws;
  size_t off = 0;
  auto alloc = [&](size_t bytes) {
    void* p = ws + off;
    off += (bytes + 255) & ~(size_t)255;
    return p;
  };
  __half* hA   = (__half*)alloc(NN * 64 * 2);
  __half* hB   = (__half*)alloc(NN * 64 * 2);
  float* xF    = (float*)alloc(NN * 64 * 4);
  float* asA   = (float*)alloc(NN * 8 * 4);
  float* adA   = (float*)alloc(NN * 8 * 4);
  float* asB   = (float*)alloc(NN * 8 * 4);
  float* adB   = (float*)alloc(NN * 8 * 4);
  int* rp_d    = (int*)alloc((NN + 1) * 4);
  int* s_d     = (int*)alloc(NE * 4);
  int* rp_e    = (int*)alloc((NN + 1) * 4);
  int* s_e     = (int*)alloc(NE * 4);
  int* totals  = (int*)alloc(2 * SCB * 4);
  char* zero0  = ws + off;
  int* cnt_d   = (int*)alloc(NN * 4);
  int* cur_d   = (int*)alloc(NN * 4);
  int* cnt_e   = (int*)alloc(NN * 4);
  int* cur_e   = (int*)alloc(NN * 4);
  size_t zbytes = (size_t)((char*)(ws + off) - zero0);

  const size_t SH = 64 * 64 * sizeof(float);
  const int NBG = NN / 4;  // 5000 (gemm)
  const int NBA = NN / 8;  // 2500 (agg, 2 nodes/wave)

  hipMemsetAsync(zero0, 0, zbytes, stream);
  hist_both_kernel<<<2 * EB, 256, 0, stream>>>(dis_idx + NE, edge_idx + NE,
                                               cnt_d, cnt_e);
  scan_local_kernel<<<2 * SCB, 256, 0, stream>>>(cnt_d, cnt_e, rp_d, rp_e, totals);
  scan_apply_kernel<<<2 * SCB, 256, 0, stream>>>(totals, rp_d, rp_e);
  scatter_both_kernel<<<2 * EB, 256, 0, stream>>>(dis_idx, edge_idx, rp_d, rp_e,
                                                  cur_d, cur_e, s_d, s_e);

  gemm_attn_kernel<<<NBG, 256, 0, stream>>>(x0, W1, as1, ad1, hA, asA, adA);

  for (int k = 0; k < 12; ++k) {
    const int* rp = (((k >> 1) & 1) == 0) ? rp_d : rp_e;
    const int* ss = (((k >> 1) & 1) == 0) ? s_d : s_e;
    if ((k & 1) == 0) {
      agg_fused_kernel<8, true, 1><<<NBA, 256, SH, stream>>>(
          hA, asA, adA, rp, ss, b1, hB, nullptr, W2, as2, ad2, asB, adB);
    } else if (k < 11) {
      agg_fused_kernel<1, false, 8><<<NBA, 256, SH, stream>>>(
          hB, asB, adB, rp, ss, b2, hA, nullptr, W1, as1, ad1, asA, adA);
    } else {
      agg_fused_kernel<1, false, 0><<<NBA, 256, 0, stream>>>(
          hB, asB, adB, rp, ss, b2, nullptr, xF, nullptr, nullptr, nullptr,
          nullptr, nullptr);
    }
  }

  poolread_kernel<<<NG, 256, 0, stream>>>(xF, batch, Wm1, bm1, Wm2, bm2, out);
}